// Round 1
// 252.519 us; speedup vs baseline: 1.2982x; 1.2982x over previous
//
#include <hip/hip_runtime.h>
#include <math.h>

// STC loss forward on MI355X — Round 13: register-resident chunk double-buffer
// (LDS eliminated from the scan) + log2-domain math + off-chain reassociation.
//
// R12 post-mortem: 294 cy/step with VGPR_Count=88 — the compiler cannot hold
// the 16-float4 chunk staged (needs 80+ regs), so it interleaves ds_read +
// lgkmcnt waits into the step stream, exposing LDS latency per step. We only
// run 1 wave/CU -> occupancy is irrelevant -> spend VGPRs instead:
//  (1) __launch_bounds__(64,1); two chunk buffers (X,Y) of NAMED float4s
//      loaded straight from global (global_load_dwordx4). Compiler emits
//      counted vmcnt waits; next chunk's loads fly under current compute.
//  (2) log2 domain: K1 stores L2E*tok and log2(q); the per-column LSE is
//      m + v_log_f32(1 + v_exp_f32(-|d|)) with NO mul on the carried chain.
//      Final score scaled by ln2 once.
//  (3) A' = (m+lq)+lz, O' = sk ? (m+tok)+lz : A+tok  — adds moved off-chain.
//  (4) DPP shift with old=NEG_INF, bound_ctrl=false: lane0's -inf comes from
//      the dpp itself, no cndmask on the chain.
//
// Per column (lane j owns cols 2j,2j+1; P = O of col-1):
//   m = max(A,P); lz = log2(1 + 2^(-|A-P|))
//   A' = (m+lq)+lz;   O' = (sk ? (m+tok)+lz : A+tok)
// ACCEPT = LSE2(O1@lane49, A0@lane50) * ln2. ws layout identical to R12.

#define T_LEN   2000
#define BATCH   32
#define NCLS    128
#define LTGT    100
#define CHUNK   16
#define NCHUNK  125          // T_LEN / CHUNK
#define NEG_INF_F (-1e30f)

#if __has_builtin(__builtin_amdgcn_exp2f)
#define EXP2(x) __builtin_amdgcn_exp2f(x)
#else
#define EXP2(x) exp2f(x)
#endif
#if __has_builtin(__builtin_amdgcn_logf)
#define LOG2(x) __builtin_amdgcn_logf(x)
#else
#define LOG2(x) __log2f(x)
#endif

// ---------------------------------------------------------------- K1: emissions
// tabA[(b*T+t)*50 + j] = (L2E*tok_2j, L2E*tok_2j+1, log2 q_2j, log2 q_2j+1)
// tabB[b*T+t] = log2(p_blank + wt*s)
__global__ void __launch_bounds__(64)
stc_emit(const float* __restrict__ inputs,   // (T,B,C) log-softmax (natural)
         const int*   __restrict__ targets,  // (B,L)
         float4*      __restrict__ tabA,
         float*       __restrict__ tabB,
         const float wt)
{
    const int t    = blockIdx.x;
    const int b    = blockIdx.y;
    const int lane = threadIdx.x;        // 1 wave per (t,b) row

    __shared__ float lps[NCLS];

    const size_t base = ((size_t)t * BATCH + b) * NCLS;
    const float2 x = *(const float2*)(inputs + base + 2 * lane);
    *(float2*)&lps[2 * lane] = x;        // same-wave DS: in-order, no barrier

    const float ex = __expf(x.x), ey = __expf(x.y);
    float ps = (lane == 0) ? ey : (ex + ey);   // s excludes blank (class 0)
    #pragma unroll
    for (int off = 32; off >= 1; off >>= 1)
        ps += __shfl_xor(ps, off, 64);
    const float pb = __shfl(ex, 0, 64);  // blank prob

    const float L2E = 1.4426950408889634f;
    if (lane < 50) {
        const int t0 = targets[b * LTGT + 2 * lane];
        const int t1 = targets[b * LTGT + 2 * lane + 1];
        const float lt0 = lps[t0], lt1 = lps[t1];
        const float aa  = fmaf(wt * (1.0f + 1e-7f), ps, pb);
        const float q0  = fmaf(-wt, __expf(lt0), aa);
        const float q1  = fmaf(-wt, __expf(lt1), aa);
        tabA[((size_t)b * T_LEN + t) * 50 + lane] =
            make_float4(L2E * lt0, L2E * lt1, LOG2(q0), LOG2(q1));
    } else if (lane == 50) {
        tabB[(size_t)b * T_LEN + t] = LOG2(fmaf(wt, ps, pb));
    }
}

// lane i <- lane i-1 across the wave64 (DPP wave_shr:1).
// bound_ctrl=false + old=NEG_INF: lane 0 receives -1e30 directly.
__device__ __forceinline__ float shift_up1_ninf(float x)
{
    return __int_as_float(
        __builtin_amdgcn_update_dpp(__float_as_int(NEG_INF_F),
                                    __float_as_int(x),
                                    0x138, 0xf, 0xf, false));
}

// ---------------------------------------------------------------- K2: scan
__global__ void __launch_bounds__(64, 1)
stc_scan(const float4* __restrict__ tabA,
         const float*  __restrict__ tabB,
         const int*    __restrict__ targets,
         float*        __restrict__ out)
{
    const int b    = blockIdx.x;
    const int lane = threadIdx.x;            // lane j owns cols 2j, 2j+1
    const bool l50 = (lane == 50);

    // skip gates as per-lane bool masks (cndmask off an SGPR pair)
    const int tb0 = b * LTGT;
    const int c0 = 2 * lane, c1 = 2 * lane + 1;
    bool skb0 = false, skb1 = false;
    if (c0 >= 1 && c0 <= 99)
        skb0 = (targets[tb0 + c0] != targets[tb0 + c0 - 1]);
    if (c1 <= 99)
        skb1 = (targets[tb0 + c1] != targets[tb0 + c1 - 1]);

    // merged log2 state: A = log2(2^E + 2^S); init alpha0 = {state0: 1}
    float A0 = (lane == 0) ? 0.0f : NEG_INF_F;
    float O0 = NEG_INF_F, A1 = NEG_INF_F, O1 = NEG_INF_F;
    float p0 = NEG_INF_F;                    // O1 of lane j-1 (prev step)

    const float4* gA = tabA + (size_t)b * T_LEN * 50 + lane;
    const float4* gQ = (const float4*)(tabB + (size_t)b * T_LEN);

    // two whole-chunk register buffers (named -> pure VGPR, no scratch)
    float4 Xv0, Xv1, Xv2, Xv3, Xv4, Xv5, Xv6, Xv7,
           Xv8, Xv9, Xv10, Xv11, Xv12, Xv13, Xv14, Xv15;
    float4 Xq0, Xq1, Xq2, Xq3;
    float4 Yv0, Yv1, Yv2, Yv3, Yv4, Yv5, Yv6, Yv7,
           Yv8, Yv9, Yv10, Yv11, Yv12, Yv13, Yv14, Yv15;
    float4 Yq0, Yq1, Yq2, Yq3;

#define LOADB(P, c) do {                                                \
        const float4* pa_ = gA + (size_t)(c) * (CHUNK * 50);            \
        P##v0  = pa_[0 * 50];   P##v1  = pa_[1 * 50];                   \
        P##v2  = pa_[2 * 50];   P##v3  = pa_[3 * 50];                   \
        P##v4  = pa_[4 * 50];   P##v5  = pa_[5 * 50];                   \
        P##v6  = pa_[6 * 50];   P##v7  = pa_[7 * 50];                   \
        P##v8  = pa_[8 * 50];   P##v9  = pa_[9 * 50];                   \
        P##v10 = pa_[10 * 50];  P##v11 = pa_[11 * 50];                  \
        P##v12 = pa_[12 * 50];  P##v13 = pa_[13 * 50];                  \
        P##v14 = pa_[14 * 50];  P##v15 = pa_[15 * 50];                  \
        const float4* pq_ = gQ + (size_t)(c) * (CHUNK / 4);             \
        P##q0 = pq_[0]; P##q1 = pq_[1]; P##q2 = pq_[2]; P##q3 = pq_[3]; \
    } while (0)

    // carried chain per step: p0 -> sub -> v_exp -> add -> v_log -> add -> cnd
    // (adds of m+tok / m+lq precomputed off-chain; DPP lane0 = -inf via old)
#define STEP(vx, vy, vz, vw, qk) do {                                  \
        /* col 1 (its O1n feeds next step's col0 via DPP) */           \
        const float m1  = fmaxf(A1, O0);                               \
        const float lz1 = LOG2(1.0f + EXP2(-fabsf(A1 - O0)));          \
        const float O1n = skb1 ? (m1 + (vy)) + lz1 : A1 + (vy);        \
        const float psh = shift_up1_ninf(O1n);                         \
        A1 = (m1 + (vw)) + lz1;                                        \
        O1 = O1n;                                                      \
        /* col 0 (uses PREVIOUS step's p0) */                          \
        const float m0  = fmaxf(A0, p0);                               \
        const float lz0 = LOG2(1.0f + EXP2(-fabsf(A0 - p0)));          \
        const float lq0 = l50 ? (qk) : (vz);                           \
        O0 = skb0 ? (m0 + (vx)) + lz0 : A0 + (vx);                     \
        A0 = (m0 + lq0) + lz0;                                         \
        p0 = psh;                                                      \
    } while (0)

#define RUNB(P) do {                                                   \
        STEP(P##v0.x,  P##v0.y,  P##v0.z,  P##v0.w,  P##q0.x);         \
        STEP(P##v1.x,  P##v1.y,  P##v1.z,  P##v1.w,  P##q0.y);         \
        STEP(P##v2.x,  P##v2.y,  P##v2.z,  P##v2.w,  P##q0.z);         \
        STEP(P##v3.x,  P##v3.y,  P##v3.z,  P##v3.w,  P##q0.w);         \
        STEP(P##v4.x,  P##v4.y,  P##v4.z,  P##v4.w,  P##q1.x);         \
        STEP(P##v5.x,  P##v5.y,  P##v5.z,  P##v5.w,  P##q1.y);         \
        STEP(P##v6.x,  P##v6.y,  P##v6.z,  P##v6.w,  P##q1.z);         \
        STEP(P##v7.x,  P##v7.y,  P##v7.z,  P##v7.w,  P##q1.w);         \
        STEP(P##v8.x,  P##v8.y,  P##v8.z,  P##v8.w,  P##q2.x);         \
        STEP(P##v9.x,  P##v9.y,  P##v9.z,  P##v9.w,  P##q2.y);         \
        STEP(P##v10.x, P##v10.y, P##v10.z, P##v10.w, P##q2.z);         \
        STEP(P##v11.x, P##v11.y, P##v11.z, P##v11.w, P##q2.w);         \
        STEP(P##v12.x, P##v12.y, P##v12.z, P##v12.w, P##q3.x);         \
        STEP(P##v13.x, P##v13.y, P##v13.z, P##v13.w, P##q3.y);         \
        STEP(P##v14.x, P##v14.y, P##v14.z, P##v14.w, P##q3.z);         \
        STEP(P##v15.x, P##v15.y, P##v15.z, P##v15.w, P##q3.w);         \
    } while (0)

    // software pipeline: consume X while Y's loads are in flight, and v.v.
    LOADB(X, 0);
    for (int c = 0; c < NCHUNK - 1; c += 2) {   // c = 0,2,...,122
        LOADB(Y, c + 1);
        RUNB(X);                                // counted vmcnt waits on X only
        LOADB(X, c + 2);                        // c+2 <= 124, always valid
        RUNB(Y);
    }
    RUNB(X);                                    // chunk 124

#undef RUNB
#undef STEP
#undef LOADB

    // ACCEPT: LSE(O_99, E_100, S_100) = LSE2(O1@49, A0@50), back to natural log
    const float vO = __shfl(O1, 49, 64);
    const float vA = __shfl(A0, 50, 64);
    if (lane == 0) {
        const float m   = fmaxf(vO, vA);
        const float lz  = LOG2(1.0f + EXP2(-fabsf(vO - vA)));
        const float LN2 = 0.6931471805599453f;
        atomicAdd(out, -(m + lz) * LN2 / ((float)T_LEN * (float)BATCH));
    }
}

// ---------------------------------------------------------------- launch
extern "C" void kernel_launch(void* const* d_in, const int* in_sizes, int n_in,
                              void* d_out, int out_size, void* d_ws, size_t ws_size,
                              hipStream_t stream)
{
    const float* inputs  = (const float*)d_in[0];   // (2000,32,128) f32
    const int*   targets = (const int*)d_in[1];     // (32,100) i32
    float*       out     = (float*)d_out;           // scalar f32

    float4* tabA = (float4*)d_ws;                                   // 51.2 MB
    float*  tabB = (float*)((char*)d_ws + (size_t)BATCH * T_LEN * 50 * 16);

    // wt = WLAST + (W0-WLAST)*exp(-NSTEP*ln2/THALF)
    const float wt = (float)(0.1 + 0.9 * exp(-log(2.0) / 10000.0));

    (void)hipMemsetAsync(out, 0, sizeof(float), stream);
    stc_emit<<<dim3(T_LEN, BATCH), dim3(64), 0, stream>>>(inputs, targets,
                                                          tabA, tabB, wt);
    stc_scan<<<dim3(BATCH), dim3(64), 0, stream>>>(tabA, tabB, targets, out);
}

// Round 3
// 195.519 us; speedup vs baseline: 1.6767x; 1.2915x over previous
//
#include <hip/hip_runtime.h>
#include <math.h>

// STC loss forward on MI355X — Round 15: R14's forced register double-buffer,
// with asm operands as BARE ext_vector types (f32x4), not HIP float4 structs.
//
// R14 post-mortem: runtime abort (GPU fault, no counters). Prime suspect:
// HIP float4 is a struct wrapping the vector -> "=&v" constraint on it is
// outside the known-good pattern; a mis-lowered operand gives a malformed
// dst tuple / garbage addr pair -> wild global_load -> memory fault.
// All asm-touched values are now `typedef float f32x4 ext_vector_type(4)`,
// the exact pattern learn_hip's asm probes use successfully.
//
// Structure (unchanged from R14):
//  - scan: per chunk (16 steps) 20 global_load_dwordx4 issued as volatile
//    inline asm (cannot sink; outputs pinned in VGPRs), double-buffered X/Y.
//    Counted s_waitcnt vmcnt(20) + sched_barrier(0) (rule #18) so chunk c's
//    compute (~600 cy VALU) overlaps chunk c+1's loads (~400-500 cy L3 lat).
//    Compiler-issued loads (targets) drained before the pipeline so manual
//    vmcnt counts are exact.
//  - emit: 4 rows per wave, unrolled -> 4 independent load->exp->reduce
//    chains interleave (was 1 serial ~1000cy chain per wave).
//
// Math (log2 domain, unchanged, bit-identical to R13 which passed):
//   m = max(A,P); lz = log2(1 + 2^(-|A-P|))
//   A' = (m+lq)+lz;   O' = (sk ? (m+tok)+lz : A+tok)
// ACCEPT = LSE2(O1@lane49, A0@lane50) * ln2.

#define T_LEN   2000
#define BATCH   32
#define NCLS    128
#define LTGT    100
#define CHUNK   16
#define NCHUNK  125          // T_LEN / CHUNK
#define ROWS_PER_WG 4
#define NEG_INF_F (-1e30f)

typedef float f32x4 __attribute__((ext_vector_type(4)));

#if __has_builtin(__builtin_amdgcn_exp2f)
#define EXP2(x) __builtin_amdgcn_exp2f(x)
#else
#define EXP2(x) exp2f(x)
#endif
#if __has_builtin(__builtin_amdgcn_logf)
#define LOG2(x) __builtin_amdgcn_logf(x)
#else
#define LOG2(x) __log2f(x)
#endif

// ---------------------------------------------------------------- K1: emissions
// tabA[(b*T+t)*50 + j] = (L2E*tok_2j, L2E*tok_2j+1, log2 q_2j, log2 q_2j+1)
// tabB[b*T+t] = log2(p_blank + wt*s)
__global__ void __launch_bounds__(64)
stc_emit(const float* __restrict__ inputs,   // (T,B,C) log-softmax (natural)
         const int*   __restrict__ targets,  // (B,L)
         float4*      __restrict__ tabA,
         float*       __restrict__ tabB,
         const float wt)
{
    const int tbase = blockIdx.x * ROWS_PER_WG;
    const int b     = blockIdx.y;
    const int lane  = threadIdx.x;       // 1 wave per block, 4 rows per wave

    __shared__ float lps[ROWS_PER_WG][NCLS];

    int tg0 = 0, tg1 = 0;
    if (lane < 50) {                     // hoisted: same for all 4 rows
        tg0 = targets[b * LTGT + 2 * lane];
        tg1 = targets[b * LTGT + 2 * lane + 1];
    }
    const float L2E = 1.4426950408889634f;

    #pragma unroll
    for (int i = 0; i < ROWS_PER_WG; ++i) {
        const int t = tbase + i;
        const size_t base = ((size_t)t * BATCH + b) * NCLS;
        const float2 x = *(const float2*)(inputs + base + 2 * lane);
        *(float2*)&lps[i][2 * lane] = x;     // same-wave DS: in-order
        const float ex = __expf(x.x), ey = __expf(x.y);
        float ps = (lane == 0) ? ey : (ex + ey);   // s excludes blank
        #pragma unroll
        for (int off = 32; off >= 1; off >>= 1)
            ps += __shfl_xor(ps, off, 64);
        const float pb = __shfl(ex, 0, 64);  // blank prob
        if (lane < 50) {
            const float lt0 = lps[i][tg0], lt1 = lps[i][tg1];
            const float aa  = fmaf(wt * (1.0f + 1e-7f), ps, pb);
            const float q0  = fmaf(-wt, __expf(lt0), aa);
            const float q1  = fmaf(-wt, __expf(lt1), aa);
            tabA[((size_t)b * T_LEN + t) * 50 + lane] =
                make_float4(L2E * lt0, L2E * lt1, LOG2(q0), LOG2(q1));
        } else if (lane == 50) {
            tabB[(size_t)b * T_LEN + t] = LOG2(fmaf(wt, ps, pb));
        }
    }
}

// lane i <- lane i-1 across the wave64 (DPP wave_shr:1).
// bound_ctrl=false + old=NEG_INF: lane 0 receives -1e30 directly.
__device__ __forceinline__ float shift_up1_ninf(float x)
{
    return __int_as_float(
        __builtin_amdgcn_update_dpp(__float_as_int(NEG_INF_F),
                                    __float_as_int(x),
                                    0x138, 0xf, 0xf, false));
}

// pinned-issue async load: volatile asm cannot be sunk; output (bare
// ext_vector) forced into a VGPR quad. No automatic waitcnt is generated
// for these -> all waits are manual (VMWAIT below).
#define GL4(dst, base, imm)                                             \
    asm volatile("global_load_dwordx4 %0, %1, off offset:" #imm         \
                 : "=&v"(dst) : "v"(base))

// counted wait + hard scheduling fence (rule #18: without sched_barrier the
// compiler hoists register-only consumers above the asm waitcnt).
#define VMWAIT(n) do {                                                  \
        asm volatile("s_waitcnt vmcnt(" #n ")" ::: "memory");           \
        __builtin_amdgcn_sched_barrier(0);                              \
    } while (0)

// ---------------------------------------------------------------- K2: scan
__global__ void __launch_bounds__(64, 1)
stc_scan(const float4* __restrict__ tabA,
         const float*  __restrict__ tabB,
         const int*    __restrict__ targets,
         float*        __restrict__ out)
{
    const int b    = blockIdx.x;
    const int lane = threadIdx.x;            // lane j owns cols 2j, 2j+1
    const bool l50 = (lane == 50);

    // skip gates as per-lane bool masks (cndmask off an SGPR pair)
    const int tb0 = b * LTGT;
    const int c0 = 2 * lane, c1 = 2 * lane + 1;
    bool skb0 = false, skb1 = false;
    if (c0 >= 1 && c0 <= 99)
        skb0 = (targets[tb0 + c0] != targets[tb0 + c0 - 1]);
    if (c1 <= 99)
        skb1 = (targets[tb0 + c1] != targets[tb0 + c1 - 1]);

    // merged log2 state: A = log2(2^E + 2^S); init alpha0 = {state0: 1}
    float A0 = (lane == 0) ? 0.0f : NEG_INF_F;
    float O0 = NEG_INF_F, A1 = NEG_INF_F, O1 = NEG_INF_F;
    float p0 = NEG_INF_F;                    // O1 of lane j-1 (prev step)

    // byte-granular bases for asm addressing
    const char* gAc = (const char*)tabA + (size_t)b * T_LEN * 800
                    + (size_t)lane * 16;
    const char* gQc = (const char*)(tabB + (size_t)b * T_LEN);

    // drain ALL compiler-issued loads (targets) so manual vmcnt counts are
    // exact from here on. No non-asm VMEM happens until the epilogue.
    asm volatile("s_waitcnt vmcnt(0) lgkmcnt(0)" ::: "memory");
    __builtin_amdgcn_sched_barrier(0);

    // two whole-chunk register buffers (asm outputs -> pinned VGPR quads)
    f32x4 Xv0, Xv1, Xv2, Xv3, Xv4, Xv5, Xv6, Xv7,
          Xv8, Xv9, Xv10, Xv11, Xv12, Xv13, Xv14, Xv15, Xq0, Xq1, Xq2, Xq3;
    f32x4 Yv0, Yv1, Yv2, Yv3, Yv4, Yv5, Yv6, Yv7,
          Yv8, Yv9, Yv10, Yv11, Yv12, Yv13, Yv14, Yv15, Yq0, Yq1, Yq2, Yq3;

    // 20 loads per chunk: 16 x A-rows (800B stride, 3 bases + imm offsets,
    // all imm <= 4000 < 4096 signed-13-bit limit) + 4 x q (wave-uniform)
#define LOADB(P, c) do {                                                \
        const char* a0_ = gAc + (size_t)(c) * (CHUNK * 800);            \
        const char* a1_ = a0_ + 4000;                                   \
        const char* a2_ = a0_ + 8000;                                   \
        GL4(P##v0,  a0_, 0);    GL4(P##v1,  a0_, 800);                  \
        GL4(P##v2,  a0_, 1600); GL4(P##v3,  a0_, 2400);                 \
        GL4(P##v4,  a0_, 3200);                                         \
        GL4(P##v5,  a1_, 0);    GL4(P##v6,  a1_, 800);                  \
        GL4(P##v7,  a1_, 1600); GL4(P##v8,  a1_, 2400);                 \
        GL4(P##v9,  a1_, 3200);                                         \
        GL4(P##v10, a2_, 0);    GL4(P##v11, a2_, 800);                  \
        GL4(P##v12, a2_, 1600); GL4(P##v13, a2_, 2400);                 \
        GL4(P##v14, a2_, 3200); GL4(P##v15, a2_, 4000);                 \
        const char* q_ = gQc + (size_t)(c) * (CHUNK * 4);               \
        GL4(P##q0, q_, 0);  GL4(P##q1, q_, 16);                         \
        GL4(P##q2, q_, 32); GL4(P##q3, q_, 48);                         \
    } while (0)

    // carried chain per step: p0 -> sub -> v_exp -> add -> v_log -> add -> cnd
#define STEP(vx, vy, vz, vw, qk) do {                                  \
        /* col 1 (its O1n feeds next step's col0 via DPP) */           \
        const float m1  = fmaxf(A1, O0);                               \
        const float lz1 = LOG2(1.0f + EXP2(-fabsf(A1 - O0)));          \
        const float O1n = skb1 ? (m1 + (vy)) + lz1 : A1 + (vy);        \
        const float psh = shift_up1_ninf(O1n);                         \
        A1 = (m1 + (vw)) + lz1;                                        \
        O1 = O1n;                                                      \
        /* col 0 (uses PREVIOUS step's p0) */                          \
        const float m0  = fmaxf(A0, p0);                               \
        const float lz0 = LOG2(1.0f + EXP2(-fabsf(A0 - p0)));          \
        const float lq0 = l50 ? (qk) : (vz);                           \
        O0 = skb0 ? (m0 + (vx)) + lz0 : A0 + (vx);                     \
        A0 = (m0 + lq0) + lz0;                                         \
        p0 = psh;                                                      \
    } while (0)

#define RUNB(P) do {                                                       \
        STEP(P##v0[0],  P##v0[1],  P##v0[2],  P##v0[3],  P##q0[0]);        \
        STEP(P##v1[0],  P##v1[1],  P##v1[2],  P##v1[3],  P##q0[1]);        \
        STEP(P##v2[0],  P##v2[1],  P##v2[2],  P##v2[3],  P##q0[2]);        \
        STEP(P##v3[0],  P##v3[1],  P##v3[2],  P##v3[3],  P##q0[3]);        \
        STEP(P##v4[0],  P##v4[1],  P##v4[2],  P##v4[3],  P##q1[0]);        \
        STEP(P##v5[0],  P##v5[1],  P##v5[2],  P##v5[3],  P##q1[1]);        \
        STEP(P##v6[0],  P##v6[1],  P##v6[2],  P##v6[3],  P##q1[2]);        \
        STEP(P##v7[0],  P##v7[1],  P##v7[2],  P##v7[3],  P##q1[3]);        \
        STEP(P##v8[0],  P##v8[1],  P##v8[2],  P##v8[3],  P##q2[0]);        \
        STEP(P##v9[0],  P##v9[1],  P##v9[2],  P##v9[3],  P##q2[1]);        \
        STEP(P##v10[0], P##v10[1], P##v10[2], P##v10[3], P##q2[2]);        \
        STEP(P##v11[0], P##v11[1], P##v11[2], P##v11[3], P##q2[3]);        \
        STEP(P##v12[0], P##v12[1], P##v12[2], P##v12[3], P##q3[0]);        \
        STEP(P##v13[0], P##v13[1], P##v13[2], P##v13[3], P##q3[1]);        \
        STEP(P##v14[0], P##v14[1], P##v14[2], P##v14[3], P##q3[2]);        \
        STEP(P##v15[0], P##v15[1], P##v15[2], P##v15[3], P##q3[3]);        \
    } while (0)

    // software pipeline, prefetch depth 1 chunk, counted waits:
    //   issue(c+1) ... wait until only c+1's 20 remain ... compute(c)
    LOADB(X, 0);                                 // 20 outstanding
    for (int c = 0; c + 1 < NCHUNK; c += 2) {    // c = 0,2,...,122
        LOADB(Y, c + 1);                         // 40 outstanding
        VMWAIT(20);                              // X(c) done, Y in flight
        RUNB(X);
        LOADB(X, c + 2);                         // c+2 <= 124, always valid
        VMWAIT(20);                              // Y(c+1) done, X in flight
        RUNB(Y);
    }
    VMWAIT(0);                                   // drain X(124)
    RUNB(X);

#undef RUNB
#undef STEP
#undef LOADB

    // ACCEPT: LSE(O_99, E_100, S_100) = LSE2(O1@49, A0@50), back to natural log
    const float vO = __shfl(O1, 49, 64);
    const float vA = __shfl(A0, 50, 64);
    if (lane == 0) {
        const float m   = fmaxf(vO, vA);
        const float lz  = LOG2(1.0f + EXP2(-fabsf(vO - vA)));
        const float LN2 = 0.6931471805599453f;
        atomicAdd(out, -(m + lz) * LN2 / ((float)T_LEN * (float)BATCH));
    }
}

// ---------------------------------------------------------------- launch
extern "C" void kernel_launch(void* const* d_in, const int* in_sizes, int n_in,
                              void* d_out, int out_size, void* d_ws, size_t ws_size,
                              hipStream_t stream)
{
    const float* inputs  = (const float*)d_in[0];   // (2000,32,128) f32
    const int*   targets = (const int*)d_in[1];     // (32,100) i32
    float*       out     = (float*)d_out;           // scalar f32

    float4* tabA = (float4*)d_ws;                                   // 51.2 MB
    float*  tabB = (float*)((char*)d_ws + (size_t)BATCH * T_LEN * 50 * 16);

    // wt = WLAST + (W0-WLAST)*exp(-NSTEP*ln2/THALF)
    const float wt = (float)(0.1 + 0.9 * exp(-log(2.0) / 10000.0));

    (void)hipMemsetAsync(out, 0, sizeof(float), stream);
    stc_emit<<<dim3(T_LEN / ROWS_PER_WG, BATCH), dim3(64), 0, stream>>>(
        inputs, targets, tabA, tabB, wt);
    stc_scan<<<dim3(BATCH), dim3(64), 0, stream>>>(tabA, tabB, targets, out);
}

// Round 4
// 138.526 us; speedup vs baseline: 2.3665x; 1.4114x over previous
//
#include <hip/hip_runtime.h>
#include <math.h>

// STC loss forward on MI355X — Round 16: bidirectional scan (fwd alpha wave +
// bwd beta wave, meet at t*=1007) halves the serial depth; emit rewritten with
// 8-row explicit phase interleaving.
//
// R15 post-mortem: forced-register double buffer landed (114.8us scan, 138
// cy/step, memory fully hidden). Remaining time is the serial LSE chain.
// The recurrence is a log-semiring matvec chain -> associative -> run from
// both ends:
//   forward : alpha'_j = LSE(A_j, O_{j-1}) + lq_j ; O'_j = (sk? LSE : A)+tok_j
//   backward: x=lq_j+bA_j, y=tok_j+bO_j, L=LSE(x,y);
//             bA'_j = L (j<=99), bA'_100 = x_100;
//             bO'_{j-1} = sk_j ? L : x  (j=1..99); bO'_99 gets x_100 from col100
//   init beta: bO[99]=0, bA[100]=0; combine: LSE_s(alpha_1007[s]+beta_1007[s])
// Merged-A is backward-legal: E,S were merged BECAUSE their outgoing edges are
// identical -> bE==bS. Forward shift = DPP wave_shr:1 (0x138); backward shift
// = DPP wave_shl:1 (0x130), lane i <- lane i+1.
//
// Emit: 4-row unroll didn't interleave (emit stuck ~80us, 0.73 TB/s). Now 8
// rows/wave with hand-separated phases: loads x8 -> LDS writes x8 -> exps x8
// -> butterfly LEVEL-MAJOR (8 independent shfls per level) -> gathers x8 ->
// stores x8. Per-row math bit-identical.

#define T_LEN   2000
#define BATCH   32
#define NCLS    128
#define LTGT    100
#define CHUNK   16
#define EROWS   8
#define NEG_INF_F (-1e30f)

typedef float f32x4 __attribute__((ext_vector_type(4)));

#if __has_builtin(__builtin_amdgcn_exp2f)
#define EXP2(x) __builtin_amdgcn_exp2f(x)
#else
#define EXP2(x) exp2f(x)
#endif
#if __has_builtin(__builtin_amdgcn_logf)
#define LOG2(x) __builtin_amdgcn_logf(x)
#else
#define LOG2(x) __log2f(x)
#endif

// ---------------------------------------------------------------- K1: emissions
// tabA[(b*T+t)*50 + j] = (L2E*tok_2j, L2E*tok_2j+1, log2 q_2j, log2 q_2j+1)
// tabB[b*T+t] = log2(p_blank + wt*s)
__global__ void __launch_bounds__(64)
stc_emit(const float* __restrict__ inputs,   // (T,B,C) log-softmax (natural)
         const int*   __restrict__ targets,  // (B,L)
         float4*      __restrict__ tabA,
         float*       __restrict__ tabB,
         const float wt)
{
    const int tbase = blockIdx.x * EROWS;
    const int b     = blockIdx.y;
    const int lane  = threadIdx.x;       // 1 wave per block, 8 rows per wave

    __shared__ float lps[EROWS][NCLS];

    int tg0 = 0, tg1 = 0;
    if (lane < 50) {                     // same gather indices for all rows
        tg0 = targets[b * LTGT + 2 * lane];
        tg1 = targets[b * LTGT + 2 * lane + 1];
    }
    const float L2E = 1.4426950408889634f;

    // phase A: 8 independent global loads (one HBM latency for all)
#define ELD(i) const float2 x##i = *(const float2*)(inputs +                 \
                   ((size_t)(tbase + (i)) * BATCH + b) * NCLS + 2 * lane);
    ELD(0) ELD(1) ELD(2) ELD(3) ELD(4) ELD(5) ELD(6) ELD(7)
#undef ELD
    // phase A2: LDS writes (same-wave DS: in-order)
#define EST(i) *(float2*)&lps[i][2 * lane] = x##i;
    EST(0) EST(1) EST(2) EST(3) EST(4) EST(5) EST(6) EST(7)
#undef EST
    // phase B: per-lane partials (bit-identical to R15 per-row math)
#define EPART(i) const float ex##i = __expf(x##i.x);                          \
                 float p##i = (lane == 0) ? __expf(x##i.y)                    \
                                          : ex##i + __expf(x##i.y);
    EPART(0) EPART(1) EPART(2) EPART(3) EPART(4) EPART(5) EPART(6) EPART(7)
#undef EPART
    // phase C: butterflies, LEVEL-major (8 independent shfls per level)
#define ERED(off) p0 += __shfl_xor(p0, off, 64); p1 += __shfl_xor(p1, off, 64);\
                  p2 += __shfl_xor(p2, off, 64); p3 += __shfl_xor(p3, off, 64);\
                  p4 += __shfl_xor(p4, off, 64); p5 += __shfl_xor(p5, off, 64);\
                  p6 += __shfl_xor(p6, off, 64); p7 += __shfl_xor(p7, off, 64);
    ERED(32) ERED(16) ERED(8) ERED(4) ERED(2) ERED(1)
#undef ERED
#define EPB(i) const float pb##i = __shfl(ex##i, 0, 64);
    EPB(0) EPB(1) EPB(2) EPB(3) EPB(4) EPB(5) EPB(6) EPB(7)
#undef EPB

    if (lane < 50) {
#define EOUT(i) do {                                                          \
        const float lt0 = lps[i][tg0], lt1 = lps[i][tg1];                     \
        const float aa  = fmaf(wt * (1.0f + 1e-7f), p##i, pb##i);             \
        const float q0  = fmaf(-wt, __expf(lt0), aa);                         \
        const float q1  = fmaf(-wt, __expf(lt1), aa);                         \
        tabA[((size_t)b * T_LEN + tbase + (i)) * 50 + lane] =                 \
            make_float4(L2E * lt0, L2E * lt1, LOG2(q0), LOG2(q1));            \
    } while (0);
        EOUT(0) EOUT(1) EOUT(2) EOUT(3) EOUT(4) EOUT(5) EOUT(6) EOUT(7)
#undef EOUT
    } else if (lane == 50) {
#define EOB(i) tabB[(size_t)b * T_LEN + tbase + (i)] =                        \
                   LOG2(fmaf(wt, p##i, pb##i));
        EOB(0) EOB(1) EOB(2) EOB(3) EOB(4) EOB(5) EOB(6) EOB(7)
#undef EOB
    }
}

// DPP wave shifts, lane-boundary value = NEG_INF via old + bound_ctrl=false.
__device__ __forceinline__ float shift_up1_ninf(float x)  // lane i <- i-1
{
    return __int_as_float(
        __builtin_amdgcn_update_dpp(__float_as_int(NEG_INF_F),
                                    __float_as_int(x), 0x138, 0xf, 0xf, false));
}
__device__ __forceinline__ float shift_dn1_ninf(float x)  // lane i <- i+1
{
    return __int_as_float(
        __builtin_amdgcn_update_dpp(__float_as_int(NEG_INF_F),
                                    __float_as_int(x), 0x130, 0xf, 0xf, false));
}

// pinned-issue async load (bare ext_vector output) + counted manual waits
#define GL4(dst, base, imm)                                             \
    asm volatile("global_load_dwordx4 %0, %1, off offset:" #imm         \
                 : "=&v"(dst) : "v"(base))
#define VMWAIT(n) do {                                                  \
        asm volatile("s_waitcnt vmcnt(" #n ")" ::: "memory");           \
        __builtin_amdgcn_sched_barrier(0);                              \
    } while (0)

// ---------------------------------------------------------------- K2: scan
__global__ void __launch_bounds__(128, 1)
stc_scan(const float4* __restrict__ tabA,
         const float*  __restrict__ tabB,
         const int*    __restrict__ targets,
         float*        __restrict__ out)
{
    const int b    = blockIdx.x;
    const int lane = threadIdx.x & 63;       // lane j owns cols 2j, 2j+1
    const int wave = threadIdx.x >> 6;       // 0 = forward, 1 = backward
    const bool l50 = (lane == 50);

    __shared__ float sb[4][64];              // beta handoff

    // skip gates (same masks serve fwd O'-gate and bwd t-gate)
    const int tb0 = b * LTGT;
    const int c0 = 2 * lane, c1 = 2 * lane + 1;
    bool skb0 = false, skb1 = false;
    if (c0 >= 1 && c0 <= 99)
        skb0 = (targets[tb0 + c0] != targets[tb0 + c0 - 1]);
    if (c1 <= 99)
        skb1 = (targets[tb0 + c1] != targets[tb0 + c1 - 1]);

    const char* gAc = (const char*)tabA + (size_t)b * T_LEN * 800
                    + (size_t)lane * 16;
    const char* gQc = (const char*)(tabB + (size_t)b * T_LEN);

    // drain compiler-issued loads so manual vmcnt counts are exact
    asm volatile("s_waitcnt vmcnt(0) lgkmcnt(0)" ::: "memory");
    __builtin_amdgcn_sched_barrier(0);

    f32x4 Xv0, Xv1, Xv2, Xv3, Xv4, Xv5, Xv6, Xv7,
          Xv8, Xv9, Xv10, Xv11, Xv12, Xv13, Xv14, Xv15, Xq0, Xq1, Xq2, Xq3;
    f32x4 Yv0, Yv1, Yv2, Yv3, Yv4, Yv5, Yv6, Yv7,
          Yv8, Yv9, Yv10, Yv11, Yv12, Yv13, Yv14, Yv15, Yq0, Yq1, Yq2, Yq3;

    // 20 loads per chunk; trow = starting time-row of the chunk
#define LOADB(P, trow) do {                                             \
        const char* a0_ = gAc + (size_t)(trow) * 800;                   \
        const char* a1_ = a0_ + 4000;                                   \
        const char* a2_ = a0_ + 8000;                                   \
        GL4(P##v0,  a0_, 0);    GL4(P##v1,  a0_, 800);                  \
        GL4(P##v2,  a0_, 1600); GL4(P##v3,  a0_, 2400);                 \
        GL4(P##v4,  a0_, 3200);                                         \
        GL4(P##v5,  a1_, 0);    GL4(P##v6,  a1_, 800);                  \
        GL4(P##v7,  a1_, 1600); GL4(P##v8,  a1_, 2400);                 \
        GL4(P##v9,  a1_, 3200);                                         \
        GL4(P##v10, a2_, 0);    GL4(P##v11, a2_, 800);                  \
        GL4(P##v12, a2_, 1600); GL4(P##v13, a2_, 2400);                 \
        GL4(P##v14, a2_, 3200); GL4(P##v15, a2_, 4000);                 \
        const char* q_ = gQc + (size_t)(trow) * 4;                      \
        GL4(P##q0, q_, 0);  GL4(P##q1, q_, 16);                         \
        GL4(P##q2, q_, 32); GL4(P##q3, q_, 48);                         \
    } while (0)

    // forward alpha state (wave0) — declared here so combine can read them
    float A0 = (lane == 0) ? 0.0f : NEG_INF_F;
    float O0 = NEG_INF_F, A1 = NEG_INF_F, O1 = NEG_INF_F;
    float p0 = NEG_INF_F;

    if (wave == 0) {
        // ---------------- forward: 63 chunks, rows 0..1007 ----------------
#define FSTEP(vx, vy, vz, vw, qk) do {                                 \
        const float m1  = fmaxf(A1, O0);                               \
        const float lz1 = LOG2(1.0f + EXP2(-fabsf(A1 - O0)));          \
        const float O1n = skb1 ? (m1 + (vy)) + lz1 : A1 + (vy);        \
        const float psh = shift_up1_ninf(O1n);                         \
        A1 = (m1 + (vw)) + lz1;                                        \
        O1 = O1n;                                                      \
        const float m0  = fmaxf(A0, p0);                               \
        const float lz0 = LOG2(1.0f + EXP2(-fabsf(A0 - p0)));          \
        const float lq0 = l50 ? (qk) : (vz);                           \
        O0 = skb0 ? (m0 + (vx)) + lz0 : A0 + (vx);                     \
        A0 = (m0 + lq0) + lz0;                                         \
        p0 = psh;                                                      \
    } while (0)
#define RUNF(P) do {                                                       \
        FSTEP(P##v0[0],  P##v0[1],  P##v0[2],  P##v0[3],  P##q0[0]);       \
        FSTEP(P##v1[0],  P##v1[1],  P##v1[2],  P##v1[3],  P##q0[1]);       \
        FSTEP(P##v2[0],  P##v2[1],  P##v2[2],  P##v2[3],  P##q0[2]);       \
        FSTEP(P##v3[0],  P##v3[1],  P##v3[2],  P##v3[3],  P##q0[3]);       \
        FSTEP(P##v4[0],  P##v4[1],  P##v4[2],  P##v4[3],  P##q1[0]);       \
        FSTEP(P##v5[0],  P##v5[1],  P##v5[2],  P##v5[3],  P##q1[1]);       \
        FSTEP(P##v6[0],  P##v6[1],  P##v6[2],  P##v6[3],  P##q1[2]);       \
        FSTEP(P##v7[0],  P##v7[1],  P##v7[2],  P##v7[3],  P##q1[3]);       \
        FSTEP(P##v8[0],  P##v8[1],  P##v8[2],  P##v8[3],  P##q2[0]);       \
        FSTEP(P##v9[0],  P##v9[1],  P##v9[2],  P##v9[3],  P##q2[1]);       \
        FSTEP(P##v10[0], P##v10[1], P##v10[2], P##v10[3], P##q2[2]);       \
        FSTEP(P##v11[0], P##v11[1], P##v11[2], P##v11[3], P##q2[3]);       \
        FSTEP(P##v12[0], P##v12[1], P##v12[2], P##v12[3], P##q3[0]);       \
        FSTEP(P##v13[0], P##v13[1], P##v13[2], P##v13[3], P##q3[1]);       \
        FSTEP(P##v14[0], P##v14[1], P##v14[2], P##v14[3], P##q3[2]);       \
        FSTEP(P##v15[0], P##v15[1], P##v15[2], P##v15[3], P##q3[3]);       \
    } while (0)
        LOADB(X, 0);
        for (int c = 0; c + 1 < 63; c += 2) {
            LOADB(Y, 16 * (c + 1)); VMWAIT(20); RUNF(X);
            LOADB(X, 16 * (c + 2)); VMWAIT(20); RUNF(Y);
        }
        VMWAIT(0); RUNF(X);                  // chunk 62 (rows 992..1007)
#undef RUNF
#undef FSTEP
    } else {
        // ---------------- backward: 62 chunks, rows 1999..1008 ------------
        float bA0 = l50 ? 0.0f : NEG_INF_F;          // bA[100] = 0
        float bA1 = NEG_INF_F;
        float bO0 = NEG_INF_F;
        float bO1 = (lane == 49) ? 0.0f : NEG_INF_F; // bO[99] = 0
#define BSTEP(vx, vy, vz, vw, qk) do {                                 \
        const float x1  = bA1 + (vw);                                  \
        const float y1  = bO1 + (vy);                                  \
        const float m1  = fmaxf(x1, y1);                               \
        const float lz1 = LOG2(1.0f + EXP2(-fabsf(x1 - y1)));          \
        const float L1  = m1 + lz1;                                    \
        const float lq0 = l50 ? (qk) : (vz);                           \
        const float x0  = bA0 + lq0;                                   \
        const float y0  = bO0 + (vx);                                  \
        const float m0  = fmaxf(x0, y0);                               \
        const float lz0 = LOG2(1.0f + EXP2(-fabsf(x0 - y0)));          \
        const float L0  = m0 + lz0;                                    \
        const float t0  = skb0 ? L0 : x0;                              \
        const float psh = shift_dn1_ninf(t0);  /* lane i <- i+1 */     \
        bO0 = skb1 ? L1 : x1;                                          \
        bA0 = l50 ? x0 : L0;                                           \
        bA1 = L1;                                                      \
        bO1 = psh;                                                     \
    } while (0)
#define RUNBK(P) do {                                                      \
        BSTEP(P##v15[0], P##v15[1], P##v15[2], P##v15[3], P##q3[3]);       \
        BSTEP(P##v14[0], P##v14[1], P##v14[2], P##v14[3], P##q3[2]);       \
        BSTEP(P##v13[0], P##v13[1], P##v13[2], P##v13[3], P##q3[1]);       \
        BSTEP(P##v12[0], P##v12[1], P##v12[2], P##v12[3], P##q3[0]);       \
        BSTEP(P##v11[0], P##v11[1], P##v11[2], P##v11[3], P##q2[3]);       \
        BSTEP(P##v10[0], P##v10[1], P##v10[2], P##v10[3], P##q2[2]);       \
        BSTEP(P##v9[0],  P##v9[1],  P##v9[2],  P##v9[3],  P##q2[1]);       \
        BSTEP(P##v8[0],  P##v8[1],  P##v8[2],  P##v8[3],  P##q2[0]);       \
        BSTEP(P##v7[0],  P##v7[1],  P##v7[2],  P##v7[3],  P##q1[3]);       \
        BSTEP(P##v6[0],  P##v6[1],  P##v6[2],  P##v6[3],  P##q1[2]);       \
        BSTEP(P##v5[0],  P##v5[1],  P##v5[2],  P##v5[3],  P##q1[1]);       \
        BSTEP(P##v4[0],  P##v4[1],  P##v4[2],  P##v4[3],  P##q1[0]);       \
        BSTEP(P##v3[0],  P##v3[1],  P##v3[2],  P##v3[3],  P##q0[3]);       \
        BSTEP(P##v2[0],  P##v2[1],  P##v2[2],  P##v2[3],  P##q0[2]);       \
        BSTEP(P##v1[0],  P##v1[1],  P##v1[2],  P##v1[3],  P##q0[1]);       \
        BSTEP(P##v0[0],  P##v0[1],  P##v0[2],  P##v0[3],  P##q0[0]);       \
    } while (0)
        LOADB(X, 1984);
        for (int k = 0; k + 1 < 61; k += 2) {
            LOADB(Y, 1984 - 16 * (k + 1)); VMWAIT(20); RUNBK(X);
            LOADB(X, 1984 - 16 * (k + 2)); VMWAIT(20); RUNBK(Y);
        }
        LOADB(Y, 1008); VMWAIT(20); RUNBK(X);  // chunk 60 (rows 1024..1039)
        VMWAIT(0); RUNBK(Y);                   // chunk 61 (rows 1008..1023)
#undef RUNBK
#undef BSTEP
        sb[0][lane] = bA0; sb[1][lane] = bA1;
        sb[2][lane] = bO0; sb[3][lane] = bO1;
    }
#undef LOADB

    __syncthreads();

    if (wave == 0) {
        // combine: LSE over all states of alpha_1007 + beta_1007
        const float bA0g = sb[0][lane], bA1g = sb[1][lane];
        const float bO0g = sb[2][lane], bO1g = sb[3][lane];
        // lane masks kill garbage (incl. possible NaN) in lanes >= 50
        const float T0 = (lane <= 50) ? A0 + bA0g : NEG_INF_F;
        const float T1 = (lane < 50)  ? A1 + bA1g : NEG_INF_F;
        const float T2 = (lane < 50)  ? O0 + bO0g : NEG_INF_F;
        const float T3 = (lane < 50)  ? O1 + bO1g : NEG_INF_F;
        float M = fmaxf(fmaxf(T0, T1), fmaxf(T2, T3));
        float S = EXP2(T0 - M) + EXP2(T1 - M) + EXP2(T2 - M) + EXP2(T3 - M);
        #pragma unroll
        for (int off = 32; off >= 1; off >>= 1) {
            const float Mo = __shfl_xor(M, off, 64);
            const float So = __shfl_xor(S, off, 64);
            const float Mn = fmaxf(M, Mo);
            S = S * EXP2(M - Mn) + So * EXP2(Mo - Mn);
            M = Mn;
        }
        if (lane == 0) {
            const float LN2 = 0.6931471805599453f;
            atomicAdd(out, -(M + LOG2(S)) * LN2
                               / ((float)T_LEN * (float)BATCH));
        }
    }
}

// ---------------------------------------------------------------- launch
extern "C" void kernel_launch(void* const* d_in, const int* in_sizes, int n_in,
                              void* d_out, int out_size, void* d_ws, size_t ws_size,
                              hipStream_t stream)
{
    const float* inputs  = (const float*)d_in[0];   // (2000,32,128) f32
    const int*   targets = (const int*)d_in[1];     // (32,100) i32
    float*       out     = (float*)d_out;           // scalar f32

    float4* tabA = (float4*)d_ws;                                   // 51.2 MB
    float*  tabB = (float*)((char*)d_ws + (size_t)BATCH * T_LEN * 50 * 16);

    // wt = WLAST + (W0-WLAST)*exp(-NSTEP*ln2/THALF)
    const float wt = (float)(0.1 + 0.9 * exp(-log(2.0) / 10000.0));

    (void)hipMemsetAsync(out, 0, sizeof(float), stream);
    stc_emit<<<dim3(T_LEN / EROWS, BATCH), dim3(64), 0, stream>>>(
        inputs, targets, tabA, tabB, wt);
    stc_scan<<<dim3(BATCH), dim3(128), 0, stream>>>(tabA, tabB, targets, out);
}